// Round 1
// baseline (113.549 us; speedup 1.0000x reference)
//
#include <hip/hip_runtime.h>
#include <hip/hip_bf16.h>
#include <math.h>

// Problem constants (from reference)
constexpr int B = 64;
constexpr int S = 2048;
constexpr int D = 512;
constexpr int NCHUNK = 8;            // s-chunks per b
constexpr int CHUNK = S / NCHUNK;    // 256 rows per block
constexpr int TS = 32;               // tile rows staged in LDS

// ---------------------------------------------------------------------------
// Kernel 1: v[c][b][d] = bias[d] + sum_e K[d][e] * c_c[b][e]
// grid: (8 d-chunks, B), block 256 (4 waves). Wave computes 16 d-rows,
// lanes cover e coalesced, shfl-reduce 4 sums.
// ---------------------------------------------------------------------------
__global__ __launch_bounds__(256) void compute_v_kernel(
    const float* __restrict__ K, const float* __restrict__ bias,
    const float* __restrict__ c1, const float* __restrict__ c2,
    const float* __restrict__ c3, const float* __restrict__ c4,
    float* __restrict__ v)
{
    const int b = blockIdx.y;
    const int dchunk = blockIdx.x;   // 64 rows each
    __shared__ float c_lds[4][D];

    const float* cptr0 = c1 + (size_t)b * D;
    const float* cptr1 = c2 + (size_t)b * D;
    const float* cptr2 = c3 + (size_t)b * D;
    const float* cptr3 = c4 + (size_t)b * D;
    for (int i = threadIdx.x; i < D; i += 256) {
        c_lds[0][i] = cptr0[i];
        c_lds[1][i] = cptr1[i];
        c_lds[2][i] = cptr2[i];
        c_lds[3][i] = cptr3[i];
    }
    __syncthreads();

    const int wave = threadIdx.x >> 6;
    const int lane = threadIdx.x & 63;

    #pragma unroll
    for (int r = 0; r < 16; ++r) {
        const int d = dchunk * 64 + wave * 16 + r;
        const float* krow = K + (size_t)d * D;
        float a0 = 0.f, a1 = 0.f, a2 = 0.f, a3 = 0.f;
        #pragma unroll
        for (int k = 0; k < D / 64; ++k) {
            const float kv = krow[k * 64 + lane];
            a0 = fmaf(kv, c_lds[0][k * 64 + lane], a0);
            a1 = fmaf(kv, c_lds[1][k * 64 + lane], a1);
            a2 = fmaf(kv, c_lds[2][k * 64 + lane], a2);
            a3 = fmaf(kv, c_lds[3][k * 64 + lane], a3);
        }
        #pragma unroll
        for (int off = 32; off; off >>= 1) {
            a0 += __shfl_xor(a0, off);
            a1 += __shfl_xor(a1, off);
            a2 += __shfl_xor(a2, off);
            a3 += __shfl_xor(a3, off);
        }
        if (lane == 0) {
            const float bv = bias[d];
            v[((size_t)0 * B + b) * D + d] = a0 + bv;
            v[((size_t)1 * B + b) * D + d] = a1 + bv;
            v[((size_t)2 * B + b) * D + d] = a2 + bv;
            v[((size_t)3 * B + b) * D + d] = a3 + bv;
        }
    }
}

// ---------------------------------------------------------------------------
// Kernel 2: fused scores + online softmax + weighted accumulation.
// grid: (NCHUNK, B), block 256 (4 waves). Single pass over sent_vec.
// Emits per-block partial (m[4], l[4], P[4][D]) for later combine.
// ---------------------------------------------------------------------------
__global__ __launch_bounds__(256) void flash_kernel(
    const float* __restrict__ sent, const float* __restrict__ v,
    float* __restrict__ partML, float* __restrict__ partP)
{
    const int b = blockIdx.y;
    const int ch = blockIdx.x;

    __shared__ float tile[TS][D];   // 64 KB
    __shared__ float v_lds[4][D];   // 8 KB
    __shared__ float sc[4][TS];
    __shared__ float wt[4][TS];

    const int t = threadIdx.x;
    const int wave = t >> 6;
    const int lane = t & 63;

    // stage v for this b
    for (int i = t; i < 4 * D; i += 256) {
        const int c = i >> 9;        // D = 512
        const int d = i & (D - 1);
        v_lds[c][d] = v[((size_t)c * B + b) * D + d];
    }

    float m0 = -INFINITY, m1 = -INFINITY, m2 = -INFINITY, m3 = -INFINITY;
    float l0 = 0.f, l1 = 0.f, l2 = 0.f, l3 = 0.f;
    float p00 = 0.f, p01 = 0.f, p02 = 0.f, p03 = 0.f;  // d = t
    float p10 = 0.f, p11 = 0.f, p12 = 0.f, p13 = 0.f;  // d = t + 256

    const size_t base = ((size_t)b * S + (size_t)ch * CHUNK) * D;

    for (int tl = 0; tl < CHUNK / TS; ++tl) {
        __syncthreads();  // prior iteration done reading tile/wt
        // ---- stage tile: TS*D floats, 16 float4 per thread, coalesced
        const float4* src = (const float4*)(sent + base + (size_t)tl * TS * D);
        float4* dst = (float4*)&tile[0][0];
        #pragma unroll
        for (int i = 0; i < (TS * D / 4) / 256; ++i)
            dst[t + i * 256] = src[t + i * 256];
        __syncthreads();

        // ---- scores: wave handles TS/4 rows, 4 c's each, shfl reduce
        #pragma unroll
        for (int rr = 0; rr < TS / 4; ++rr) {
            const int r = wave * (TS / 4) + rr;
            float a0 = 0.f, a1 = 0.f, a2 = 0.f, a3 = 0.f;
            #pragma unroll
            for (int k = 0; k < D / 64; ++k) {
                const float sv = tile[r][k * 64 + lane];
                a0 = fmaf(sv, v_lds[0][k * 64 + lane], a0);
                a1 = fmaf(sv, v_lds[1][k * 64 + lane], a1);
                a2 = fmaf(sv, v_lds[2][k * 64 + lane], a2);
                a3 = fmaf(sv, v_lds[3][k * 64 + lane], a3);
            }
            #pragma unroll
            for (int off = 32; off; off >>= 1) {
                a0 += __shfl_xor(a0, off);
                a1 += __shfl_xor(a1, off);
                a2 += __shfl_xor(a2, off);
                a3 += __shfl_xor(a3, off);
            }
            if (lane == 0) {
                sc[0][r] = a0; sc[1][r] = a1; sc[2][r] = a2; sc[3][r] = a3;
            }
        }
        __syncthreads();

        // ---- online-softmax update (redundant per thread; broadcast reads)
        float n0, n1, n2, n3;
        {
            float tm0 = sc[0][0], tm1 = sc[1][0], tm2 = sc[2][0], tm3 = sc[3][0];
            #pragma unroll
            for (int r = 1; r < TS; ++r) {
                tm0 = fmaxf(tm0, sc[0][r]);
                tm1 = fmaxf(tm1, sc[1][r]);
                tm2 = fmaxf(tm2, sc[2][r]);
                tm3 = fmaxf(tm3, sc[3][r]);
            }
            n0 = fmaxf(m0, tm0); n1 = fmaxf(m1, tm1);
            n2 = fmaxf(m2, tm2); n3 = fmaxf(m3, tm3);
        }
        const float cr0 = __expf(m0 - n0), cr1 = __expf(m1 - n1);
        const float cr2 = __expf(m2 - n2), cr3 = __expf(m3 - n3);
        m0 = n0; m1 = n1; m2 = n2; m3 = n3;
        p00 *= cr0; p10 *= cr0; l0 *= cr0;
        p01 *= cr1; p11 *= cr1; l1 *= cr1;
        p02 *= cr2; p12 *= cr2; l2 *= cr2;
        p03 *= cr3; p13 *= cr3; l3 *= cr3;

        // weights -> LDS (threads 0..127), static m select via chain
        if (t < 4 * TS) {
            const int c = t >> 5;         // TS = 32
            const int r = t & (TS - 1);
            const float mc = (c == 0) ? n0 : (c == 1) ? n1 : (c == 2) ? n2 : n3;
            wt[c][r] = __expf(sc[c][r] - mc);
        }
        __syncthreads();

        // ---- accumulate P and l
        #pragma unroll 4
        for (int r = 0; r < TS; ++r) {
            const float x0 = tile[r][t];
            const float x1 = tile[r][t + 256];
            const float w0 = wt[0][r], w1 = wt[1][r], w2 = wt[2][r], w3 = wt[3][r];
            l0 += w0; l1 += w1; l2 += w2; l3 += w3;
            p00 = fmaf(w0, x0, p00); p10 = fmaf(w0, x1, p10);
            p01 = fmaf(w1, x0, p01); p11 = fmaf(w1, x1, p11);
            p02 = fmaf(w2, x0, p02); p12 = fmaf(w2, x1, p12);
            p03 = fmaf(w3, x0, p03); p13 = fmaf(w3, x1, p13);
        }
    }

    // ---- write partials
    const size_t pbase = (size_t)(b * NCHUNK + ch) * 4;
    partP[(pbase + 0) * D + t] = p00; partP[(pbase + 0) * D + t + 256] = p10;
    partP[(pbase + 1) * D + t] = p01; partP[(pbase + 1) * D + t + 256] = p11;
    partP[(pbase + 2) * D + t] = p02; partP[(pbase + 2) * D + t + 256] = p12;
    partP[(pbase + 3) * D + t] = p03; partP[(pbase + 3) * D + t + 256] = p13;
    if (t == 0) {
        partML[(pbase + 0) * 2 + 0] = m0; partML[(pbase + 0) * 2 + 1] = l0;
        partML[(pbase + 1) * 2 + 0] = m1; partML[(pbase + 1) * 2 + 1] = l1;
        partML[(pbase + 2) * 2 + 0] = m2; partML[(pbase + 2) * 2 + 1] = l2;
        partML[(pbase + 3) * 2 + 0] = m3; partML[(pbase + 3) * 2 + 1] = l3;
    }
}

// ---------------------------------------------------------------------------
// Kernel 3: combine NCHUNK partials per (c,b): global softmax merge + divide.
// grid: 4*B blocks, 128 threads (4 d each, float4).
// ---------------------------------------------------------------------------
__global__ __launch_bounds__(128) void combine_kernel(
    const float* __restrict__ partML, const float* __restrict__ partP,
    float* __restrict__ out)
{
    const int c = blockIdx.x & 3;
    const int b = blockIdx.x >> 2;
    const int t = threadIdx.x;

    float mi[NCHUNK], li[NCHUNK];
    float mg = -INFINITY;
    #pragma unroll
    for (int i = 0; i < NCHUNK; ++i) {
        const size_t pb = (size_t)(b * NCHUNK + i) * 4 + c;
        mi[i] = partML[pb * 2 + 0];
        li[i] = partML[pb * 2 + 1];
        mg = fmaxf(mg, mi[i]);
    }
    float lg = 0.f;
    float scale[NCHUNK];
    #pragma unroll
    for (int i = 0; i < NCHUNK; ++i) {
        scale[i] = __expf(mi[i] - mg);
        lg += scale[i] * li[i];
    }
    const float inv = 1.f / lg;

    float4 acc = make_float4(0.f, 0.f, 0.f, 0.f);
    #pragma unroll
    for (int i = 0; i < NCHUNK; ++i) {
        const size_t pb = (size_t)(b * NCHUNK + i) * 4 + c;
        const float4 p = *(const float4*)(partP + pb * D + t * 4);
        acc.x = fmaf(scale[i], p.x, acc.x);
        acc.y = fmaf(scale[i], p.y, acc.y);
        acc.z = fmaf(scale[i], p.z, acc.z);
        acc.w = fmaf(scale[i], p.w, acc.w);
    }
    acc.x *= inv; acc.y *= inv; acc.z *= inv; acc.w *= inv;
    *(float4*)(out + ((size_t)c * B + b) * D + t * 4) = acc;
}

// ---------------------------------------------------------------------------
extern "C" void kernel_launch(void* const* d_in, const int* in_sizes, int n_in,
                              void* d_out, int out_size, void* d_ws, size_t ws_size,
                              hipStream_t stream)
{
    const float* sent = (const float*)d_in[0];
    const float* c1   = (const float*)d_in[1];
    const float* c2   = (const float*)d_in[2];
    const float* c3   = (const float*)d_in[3];
    const float* c4   = (const float*)d_in[4];
    const float* K    = (const float*)d_in[5];
    const float* bias = (const float*)d_in[6];
    float* out = (float*)d_out;

    // workspace layout
    float* v      = (float*)d_ws;                              // 4*B*D = 512 KB
    float* partML = (float*)((char*)d_ws + 4 * B * D * 4);     // 16 KB
    float* partP  = (float*)((char*)d_ws + 4 * B * D * 4 + B * NCHUNK * 4 * 2 * 4);

    compute_v_kernel<<<dim3(8, B), 256, 0, stream>>>(K, bias, c1, c2, c3, c4, v);
    flash_kernel<<<dim3(NCHUNK, B), 256, 0, stream>>>(sent, v, partML, partP);
    combine_kernel<<<4 * B, 128, 0, stream>>>(partML, partP, out);
}